// Round 10
// baseline (151.775 us; speedup 1.0000x reference)
//
#include <hip/hip_runtime.h>
#include <hip/hip_bf16.h>

// MDTA: LN -> 1x1 conv (QKV) -> dw3x3 -> spatial attention (N=4096, d=24, 8 heads) -> proj + residual
// Round 21: slim-wave flash. R20's explicit pipeline regressed (134.0 vs R8 131.2) -> compiler
// already interleaves; the real cap is residency: 4-fragment wave state ~96-128 unified regs
// -> 4 waves/SIMD, latency-bound at ~2x issue floor. This round: 2 q-fragments/wave + 32-key
// inner step -> ~60 unified regs -> 8 waves/SIMD naturally (NO launch_bounds min-wave pin,
// R17 lesson: pinning causes spill; occupancy follows actual allocation). Grid 2048 (qb 0..31),
// NSPLIT stays 8 (R18: bigger opart thrashes XCD L2). K/V loads shared across both fragments;
// P layout = 4 chunks x 16q x 8keys, one ds_read_b128 per fragment-step (R8 scheme halved).
// ln_qkv / dwconv / gemm_proj byte-identical to R8 (best, 131.2us). setprio kept (R19 win).

typedef __bf16 bf16;
typedef __bf16 bf16x2 __attribute__((ext_vector_type(2)));
typedef __bf16 bf16x4 __attribute__((ext_vector_type(4)));
typedef __bf16 bf16x8 __attribute__((ext_vector_type(8)));
typedef float f32x4 __attribute__((ext_vector_type(4)));

#define C_DIM 192
#define N_PIX 4096
#define HEADS 8
#define DHEAD 24
#define DPAD 32
#define C3 576
#define NSPLIT 8

__device__ inline float fast_exp2(float x) {
#if __has_builtin(__builtin_amdgcn_exp2f)
    return __builtin_amdgcn_exp2f(x);
#else
    return exp2f(x);
#endif
}

__device__ inline f32x4 mfma16(bf16x8 a, bf16x8 b, f32x4 c) {
    return __builtin_amdgcn_mfma_f32_16x16x32_bf16(a, b, c, 0, 0, 0);
}

// ---------------- fused LN + QKV GEMM (64x64 tile): qkv[576,4096] = wqkv[576,192] * LN(x)[4096,192]^T ----------------
__global__ __launch_bounds__(256) void ln_qkv(const float* __restrict__ x,
                                              const float* __restrict__ gamma,
                                              const float* __restrict__ beta,
                                              const float* __restrict__ wqkv,
                                              bf16* __restrict__ qkvb,
                                              float* __restrict__ maxk2) {
    __shared__ __align__(16) bf16 Bt[64 * 200];   // 25.6 KB, +8 pad breaks 32-bank stride
    __shared__ float gs[C_DIM], bs[C_DIM];
    const int K = C_DIM;
    int n0 = blockIdx.x * 64;
    int m0 = blockIdx.y * 64;
    int t = threadIdx.x;
    if (t < C_DIM) { gs[t] = gamma[t]; bs[t] = beta[t]; }
    if (blockIdx.x == 0 && blockIdx.y == 0 && t < 8) maxk2[t] = 0.0f;
    __syncthreads();

    int lane = t & 63, wave = t >> 6;
    {
        int pl = wave * 16 + (lane & 15);       // pixel within tile, 0..63
        int seg = lane >> 4;                    // 0..3 -> 48 channels each
        int p = n0 + pl;
        float v[48];
        float s = 0.f, ss = 0.f;
        for (int j = 0; j < 48; ++j) {
            float f = x[(seg * 48 + j) * N_PIX + p];
            v[j] = f; s += f; ss += f * f;
        }
        s += __shfl_xor(s, 16, 64); s += __shfl_xor(s, 32, 64);
        ss += __shfl_xor(ss, 16, 64); ss += __shfl_xor(ss, 32, 64);
        float mean = s * (1.0f / C_DIM);
        float var = ss * (1.0f / C_DIM) - mean * mean;
        float rstd = rsqrtf(var + 1e-5f);
        bf16* dst = Bt + pl * 200 + seg * 48;
        for (int g = 0; g < 6; ++g) {
            bf16x8 w;
            for (int j = 0; j < 8; ++j) {
                int c = seg * 48 + g * 8 + j;
                w[j] = (bf16)((v[g * 8 + j] - mean) * rstd * gs[c] + bs[c]);
            }
            *(bf16x8*)(dst + g * 8) = w;
        }
    }
    __syncthreads();

    int l16 = lane & 15, quad = lane >> 4;
    int wm = (wave >> 1) * 32, wn = (wave & 1) * 32;
    f32x4 acc[2][2] = {};
    for (int kk = 0; kk < K; kk += 32) {
        const f32x4* ar0 = (const f32x4*)(wqkv + (m0 + wm + l16) * K + kk + quad * 8);
        const f32x4* ar1 = (const f32x4*)(wqkv + (m0 + wm + 16 + l16) * K + kk + quad * 8);
        f32x4 w0a = ar0[0], w0b = ar0[1];
        f32x4 w1a = ar1[0], w1b = ar1[1];
        bf16x8 a0, a1;
        for (int j = 0; j < 4; ++j) {
            a0[j] = (bf16)w0a[j]; a0[4 + j] = (bf16)w0b[j];
            a1[j] = (bf16)w1a[j]; a1[4 + j] = (bf16)w1b[j];
        }
        bf16x8 b0 = *(const bf16x8*)(Bt + (wn + l16) * 200 + kk + quad * 8);
        bf16x8 b1 = *(const bf16x8*)(Bt + (wn + 16 + l16) * 200 + kk + quad * 8);
        acc[0][0] = mfma16(a0, b0, acc[0][0]);
        acc[0][1] = mfma16(a0, b1, acc[0][1]);
        acc[1][0] = mfma16(a1, b0, acc[1][0]);
        acc[1][1] = mfma16(a1, b1, acc[1][1]);
    }
    for (int i = 0; i < 2; ++i)
        for (int j = 0; j < 2; ++j)
            for (int r = 0; r < 4; ++r) {
                int row = m0 + wm + i * 16 + quad * 4 + r;
                int col = n0 + wn + j * 16 + l16;
                qkvb[(size_t)row * N_PIX + col] = (bf16)acc[i][j][r];
            }
}

// ---------------- depthwise 3x3 + bias, vectorized; q/k stores via LDS transpose ----------------
__global__ __launch_bounds__(256) void dwconv(const bf16* __restrict__ qkv,
                                              const float* __restrict__ wdw,
                                              const float* __restrict__ bdw,
                                              bf16* __restrict__ qt,
                                              bf16* __restrict__ kt,
                                              bf16* __restrict__ vl,
                                              float* __restrict__ maxk2) {
    __shared__ float k2s[24][64];
    __shared__ bf16 stg[64 * DPAD];   // [px][ch], 4 KB
    int bx = blockIdx.x;
    int part = bx >> 9;            // 512 blocks per part
    int h = (bx >> 6) & 7;
    int y = bx & 63;
    int t = threadIdx.x;
    int ch_local = t >> 3;         // 0..31 (24 active)
    int seg = t & 7;
    int px0 = seg * 8;
    bool active = ch_local < 24;

    float acc[8];
    if (active) {
        int ch = part * C_DIM + h * DHEAD + ch_local;
        const bf16* in = qkv + (size_t)ch * N_PIX;
        float w[9];
        for (int i = 0; i < 9; ++i) w[i] = wdw[ch * 9 + i];
        float bias = bdw[ch];
        float rowv[3][10];
        for (int r = 0; r < 3; ++r) {
            int yy = y + r - 1;
            if (yy >= 0 && yy < 64) {
                bf16x8 v8 = *(const bf16x8*)(in + yy * 64 + px0);
                for (int j = 0; j < 8; ++j) rowv[r][j + 1] = (float)v8[j];
                rowv[r][0] = (seg > 0) ? (float)in[yy * 64 + px0 - 1] : 0.f;
                rowv[r][9] = (seg < 7) ? (float)in[yy * 64 + px0 + 8] : 0.f;
            } else {
                for (int j = 0; j < 10; ++j) rowv[r][j] = 0.f;
            }
        }
        for (int j = 0; j < 8; ++j) {
            float a = bias;
            for (int r = 0; r < 3; ++r)
                a += w[r * 3 + 0] * rowv[r][j] + w[r * 3 + 1] * rowv[r][j + 1]
                   + w[r * 3 + 2] * rowv[r][j + 2];
            acc[j] = a;
        }
    }

    if (part == 2) {
        if (active) {
            bf16x8 v8;
            for (int j = 0; j < 8; ++j) v8[j] = (bf16)acc[j];
            *(bf16x8*)(vl + ((size_t)(h * DPAD + ch_local)) * N_PIX + y * 64 + px0) = v8;
        } else {
            int i = t - 192;           // pad rows 24..31 x 8 segments
            int dd = 24 + (i >> 3);
            int s2 = i & 7;
            bf16 val = (bf16)((dd == 24) ? 1.0f : 0.0f);
            bf16x8 v8;
            for (int j = 0; j < 8; ++j) v8[j] = val;
            *(bf16x8*)(vl + ((size_t)(h * DPAD + dd)) * N_PIX + y * 64 + s2 * 8) = v8;
        }
    } else {
        if (active) {
            for (int j = 0; j < 8; ++j)
                stg[(px0 + j) * DPAD + ch_local] = (bf16)acc[j];
        } else {
            int i = t - 192;           // px = i: zero pad ch 24..31
            bf16x8 z;
            for (int j = 0; j < 8; ++j) z[j] = (bf16)0.0f;
            *(bf16x8*)(stg + i * DPAD + 24) = z;
        }
        if (part == 1 && active)
            for (int j = 0; j < 8; ++j) k2s[ch_local][px0 + j] = acc[j] * acc[j];
        __syncthreads();
        bf16* dst = (part == 0 ? qt : kt) + ((size_t)h * N_PIX + y * 64) * DPAD;
        *(bf16x8*)(dst + t * 8) = *(const bf16x8*)(stg + t * 8);
        if (part == 1 && t < 64) {
            float s = 0.f;
            for (int c = 0; c < 24; ++c) s += k2s[c][t];
            for (int off = 1; off < 64; off <<= 1)
                s = fmaxf(s, __shfl_xor(s, off, 64));
            if (t == 0) atomicMax((unsigned int*)(maxk2 + h), __float_as_uint(s));
        }
    }
}

// ---------------- flash attention: slim waves (2 q-fragments, 32-key step), LDS-P, split-K=8 ----------------
__global__ __launch_bounds__(256, 4) void flash_attn(const bf16* __restrict__ qt,
                                                     const bf16* __restrict__ kt,
                                                     const bf16* __restrict__ vl,
                                                     const float* __restrict__ temp,
                                                     const float* __restrict__ maxk2,
                                                     bf16* __restrict__ opart,
                                                     bf16* __restrict__ lpart) {
    __shared__ __align__(16) bf16 Plds[4 * 1024];  // 2KB/wave: 2 fragments x 1KB (private, no aliasing)

    int tid = threadIdx.x;
    int wave = tid >> 6, lane = tid & 63;
    int l16 = lane & 15, quad = lane >> 4;
    int head = blockIdx.x & 7;               // block -> XCD round-robin: head pinned per XCD
    int qb = (blockIdx.x >> 3) & 31;         // 0..31 (128 q-rows per block)
    int split = blockIdx.x >> 8;             // 0..7
    int nbase = qb * 128 + wave * 32;
    float tl = temp[head] * 1.44269504f;

    const bf16* qrow = qt + ((size_t)head * N_PIX + nbase) * DPAD;
    bf16x8 aq[2];
    for (int f = 0; f < 2; ++f)
        aq[f] = *(const bf16x8*)(qrow + (size_t)(f * 16 + l16) * DPAD + quad * 8);

    float mk2 = maxk2[head];
    float Bb[2];
    for (int f = 0; f < 2; ++f) {
        float q2 = 0.f;
        for (int j = 0; j < 8; ++j) { float v = (float)aq[f][j]; q2 += v * v; }
        q2 += __shfl_xor(q2, 16, 64);
        q2 += __shfl_xor(q2, 32, 64);
        Bb[f] = fabsf(tl) * sqrtf(q2 * mk2) + 1.0f;
    }

    const bf16* kbase = kt + (size_t)head * N_PIX * DPAD;
    const bf16* vbase = vl + (size_t)head * DPAD * N_PIX;
    bf16* pw = Plds + wave * 1024;           // 2 x 512 bf16 per wave

    f32x4 o0[2] = {}, o1[2] = {};

    const int NITER = N_PIX / NSPLIT / 32;   // 16
    int mbase = split * NITER * 32;

    #pragma unroll 1
    for (int it = 0; it < NITER; ++it) {
        int m0 = mbase + it * 32;
        // K fragments for this 32-key tile (shared by both q-fragments)
        bf16x8 ak0 = *(const bf16x8*)(kbase + (size_t)(m0 + l16) * DPAD + quad * 8);
        bf16x8 ak1 = *(const bf16x8*)(kbase + (size_t)(m0 + 16 + l16) * DPAD + quad * 8);
        // V fragments (shared by both q-fragments): lane supplies keys m0+quad*8..+7
        bf16x8 avl = *(const bf16x8*)(vbase + (size_t)l16 * N_PIX + m0 + quad * 8);
        bf16x8 avh = *(const bf16x8*)(vbase + (size_t)(16 + l16) * N_PIX + m0 + quad * 8);

        for (int f = 0; f < 2; ++f) {
            bf16* pwf = pw + f * 512;        // private region per fragment -> no false DS deps
            f32x4 z = {0.f, 0.f, 0.f, 0.f};
            __builtin_amdgcn_s_setprio(1);
            f32x4 st0 = mfma16(ak0, aq[f], z);
            f32x4 st1 = mfma16(ak1, aq[f], z);
            __builtin_amdgcn_s_setprio(0);
            // P: lane holds keys 16mt+4quad+r; chunk c=2mt+(quad>>1) holds keys 8c+4(quad&1)+r
            bf16x4 pk0, pk1;
            for (int r = 0; r < 4; ++r) {
                pk0[r] = (bf16)fast_exp2(__builtin_fmaf(st0[r], tl, -Bb[f]));
                pk1[r] = (bf16)fast_exp2(__builtin_fmaf(st1[r], tl, -Bb[f]));
            }
            *(bf16x4*)(pwf + (((quad >> 1)) * 16 + l16) * 8 + (quad & 1) * 4) = pk0;
            *(bf16x4*)(pwf + ((2 + (quad >> 1)) * 16 + l16) * 8 + (quad & 1) * 4) = pk1;
            // B operand: lane reads chunk=quad (keys 8quad..8quad+7) at q=l16
            bf16x8 ap = *(const bf16x8*)(pwf + (quad * 16 + l16) * 8);
            __builtin_amdgcn_s_setprio(1);
            o0[f] = mfma16(avl, ap, o0[f]);
            o1[f] = mfma16(avh, ap, o1[f]);
            __builtin_amdgcn_s_setprio(0);
        }
    }

    for (int f = 0; f < 2; ++f) {
        int n = nbase + f * 16 + l16;
        size_t rowo = ((size_t)(split * 8 + head) * N_PIX + n) * 24;
        bf16x4 w0;
        for (int r = 0; r < 4; ++r) w0[r] = (bf16)o0[f][r];
        *(bf16x4*)(opart + rowo + quad * 4) = w0;
        if (quad < 2) {
            bf16x4 w1;
            for (int r = 0; r < 4; ++r) w1[r] = (bf16)o1[f][r];
            *(bf16x4*)(opart + rowo + 16 + quad * 4) = w1;
        }
        if (quad == 2)
            lpart[(size_t)(split * 8 + head) * N_PIX + n] = (bf16)o1[f][0];
    }
}

// ---------------- proj GEMM with fused split-K combine; wproj converted inline ----------------
__global__ __launch_bounds__(256) void gemm_proj(const float* __restrict__ wproj,
                                                 const bf16* __restrict__ opart,
                                                 const bf16* __restrict__ lpart,
                                                 float* __restrict__ outf,
                                                 const float* __restrict__ resid) {
    __shared__ __align__(16) bf16 Bld[32 * 200];
    const int K = C_DIM;
    int n0 = blockIdx.x * 32;
    int m0 = blockIdx.y * 64;
    int t = threadIdx.x;
    {
        int h = t >> 5, nl = t & 31;
        int n = n0 + nl;
        float acc[24];
        for (int j = 0; j < 24; ++j) acc[j] = 0.f;
        float l = 0.f;
        for (int s = 0; s < NSPLIT; ++s) {
            const bf16* row = opart + ((size_t)(s * 8 + h) * N_PIX + n) * 24;
            bf16x8 a = *(const bf16x8*)(row);
            bf16x8 b = *(const bf16x8*)(row + 8);
            bf16x8 c = *(const bf16x8*)(row + 16);
            for (int j = 0; j < 8; ++j) {
                acc[j] += (float)a[j];
                acc[8 + j] += (float)b[j];
                acc[16 + j] += (float)c[j];
            }
            l += (float)lpart[(size_t)(s * 8 + h) * N_PIX + n];
        }
        float inv = 1.0f / l;
        bf16* dst = Bld + nl * 200 + h * 24;
        for (int g = 0; g < 3; ++g) {
            bf16x8 w;
            for (int j = 0; j < 8; ++j) w[j] = (bf16)(acc[g * 8 + j] * inv);
            *(bf16x8*)(dst + g * 8) = w;
        }
    }
    __syncthreads();
    int wave = t >> 6, lane = t & 63;
    int l16 = lane & 15, quad = lane >> 4;
    int mrow = m0 + wave * 16;
    float rv[8];
    for (int j = 0; j < 2; ++j)
        for (int r = 0; r < 4; ++r)
            rv[j * 4 + r] = resid[(size_t)(mrow + quad * 4 + r) * N_PIX + n0 + j * 16 + l16];
    f32x4 acc2[2] = {};
    for (int kk = 0; kk < K; kk += 32) {
        const f32x4* ar = (const f32x4*)(wproj + (mrow + l16) * K + kk + quad * 8);
        f32x4 wa = ar[0], wb = ar[1];
        bf16x8 a;
        for (int j = 0; j < 4; ++j) { a[j] = (bf16)wa[j]; a[4 + j] = (bf16)wb[j]; }
        bf16x8 b0 = *(const bf16x8*)(Bld + l16 * 200 + kk + quad * 8);
        bf16x8 b1 = *(const bf16x8*)(Bld + (16 + l16) * 200 + kk + quad * 8);
        acc2[0] = mfma16(a, b0, acc2[0]);
        acc2[1] = mfma16(a, b1, acc2[1]);
    }
    for (int j = 0; j < 2; ++j)
        for (int r = 0; r < 4; ++r) {
            int row = mrow + quad * 4 + r;
            int col = n0 + j * 16 + l16;
            outf[(size_t)row * N_PIX + col] = acc2[j][r] + rv[j * 4 + r];
        }
}

extern "C" void kernel_launch(void* const* d_in, const int* in_sizes, int n_in,
                              void* d_out, int out_size, void* d_ws, size_t ws_size,
                              hipStream_t stream) {
    const float* x     = (const float*)d_in[0];
    const float* gamma = (const float*)d_in[1];
    const float* beta  = (const float*)d_in[2];
    const float* wqkv  = (const float*)d_in[3];
    const float* wdw   = (const float*)d_in[4];
    const float* bdw   = (const float*)d_in[5];
    const float* wproj = (const float*)d_in[6];
    const float* temp  = (const float*)d_in[7];
    float* out = (float*)d_out;

    char* ws = (char*)d_ws;
    bf16* qkv     = (bf16*)(ws + 0);          // 576*4096*2 = 4718592
    bf16* qt      = (bf16*)(ws + 4718592);    // 2097152
    bf16* kt      = (bf16*)(ws + 6815744);    // 2097152
    bf16* vl      = (bf16*)(ws + 8912896);    // 2097152
    bf16* opart   = (bf16*)(ws + 11010048);   // 8*8*4096*24*2 = 12582912
    bf16* lpart   = (bf16*)(ws + 23592960);   // 8*8*4096*2 = 524288
    float* maxk2  = (float*)(ws + 24117248);  // 32

    ln_qkv<<<dim3(64, 9), 256, 0, stream>>>(x, gamma, beta, wqkv, qkv, maxk2);
    dwconv<<<1536, 256, 0, stream>>>(qkv, wdw, bdw, qt, kt, vl, maxk2);
    flash_attn<<<2048, 256, 0, stream>>>(qt, kt, vl, temp, maxk2, opart, lpart);
    gemm_proj<<<dim3(128, 3), 256, 0, stream>>>(wproj, opart, lpart, out, x);
}

// Round 11
// 131.045 us; speedup vs baseline: 1.1582x; 1.1582x over previous
//
#include <hip/hip_runtime.h>
#include <hip/hip_bf16.h>

// MDTA: LN -> 1x1 conv (QKV) -> dw3x3 -> spatial attention (N=4096, d=24, 8 heads) -> proj + residual
// Round 22: RESTORE R19/R8 (proven best, 131.2us) after R21's slim-wave regression (151.8;
// occupancy 60% but flash 52.8us -> occupancy was never the binding constraint; 4-fragment
// per-wave ILP + K-prefetch pipeline is worth more than 2x resident waves).
// Falsified-hypotheses ledger: coop mega-kernel +480us (grid.sync spin + VGPR squeeze);
// register-P +12us (repack VALU + cvt chain feeds MFMA); NSPLIT=16 +28us (opart thrashes
// 4MB/XCD L2; residency reg-capped anyway); launch_bounds(,8) pin = spill catastrophe
// (VGPR 32, 1.1GB scratch); explicit fragment SWP +2.8us (compiler already interleaves;
// added live-range pressure); slim-wave +20us (halved ILP, lost prefetch, doubled overhead).
// P-LDS access is throughput-balanced (8 lanes/4-bank group on b128, 4 lanes/bank-pair on
// b64 = 128B/cyc floor) -> the 2.1M bank-conflict counts are replay-at-floor, not a loss.
// Accounting: 131.2 = ~84us harness poison-fills (2x268MB, immovable) + ~47us pipeline
// (flash ~31 vs ~13 floor: latency-bound at the unified-RF-capped 4 waves/SIMD).

typedef __bf16 bf16;
typedef __bf16 bf16x2 __attribute__((ext_vector_type(2)));
typedef __bf16 bf16x4 __attribute__((ext_vector_type(4)));
typedef __bf16 bf16x8 __attribute__((ext_vector_type(8)));
typedef float f32x4 __attribute__((ext_vector_type(4)));

#define C_DIM 192
#define N_PIX 4096
#define HEADS 8
#define DHEAD 24
#define DPAD 32
#define C3 576
#define NSPLIT 8

__device__ inline float fast_exp2(float x) {
#if __has_builtin(__builtin_amdgcn_exp2f)
    return __builtin_amdgcn_exp2f(x);
#else
    return exp2f(x);
#endif
}

__device__ inline f32x4 mfma16(bf16x8 a, bf16x8 b, f32x4 c) {
    return __builtin_amdgcn_mfma_f32_16x16x32_bf16(a, b, c, 0, 0, 0);
}

// ---------------- fused LN + QKV GEMM (64x64 tile): qkv[576,4096] = wqkv[576,192] * LN(x)[4096,192]^T ----------------
__global__ __launch_bounds__(256) void ln_qkv(const float* __restrict__ x,
                                              const float* __restrict__ gamma,
                                              const float* __restrict__ beta,
                                              const float* __restrict__ wqkv,
                                              bf16* __restrict__ qkvb,
                                              float* __restrict__ maxk2) {
    __shared__ __align__(16) bf16 Bt[64 * 200];   // 25.6 KB, +8 pad breaks 32-bank stride
    __shared__ float gs[C_DIM], bs[C_DIM];
    const int K = C_DIM;
    int n0 = blockIdx.x * 64;
    int m0 = blockIdx.y * 64;
    int t = threadIdx.x;
    if (t < C_DIM) { gs[t] = gamma[t]; bs[t] = beta[t]; }
    if (blockIdx.x == 0 && blockIdx.y == 0 && t < 8) maxk2[t] = 0.0f;
    __syncthreads();

    int lane = t & 63, wave = t >> 6;
    {
        int pl = wave * 16 + (lane & 15);       // pixel within tile, 0..63
        int seg = lane >> 4;                    // 0..3 -> 48 channels each
        int p = n0 + pl;
        float v[48];
        float s = 0.f, ss = 0.f;
        for (int j = 0; j < 48; ++j) {
            float f = x[(seg * 48 + j) * N_PIX + p];
            v[j] = f; s += f; ss += f * f;
        }
        s += __shfl_xor(s, 16, 64); s += __shfl_xor(s, 32, 64);
        ss += __shfl_xor(ss, 16, 64); ss += __shfl_xor(ss, 32, 64);
        float mean = s * (1.0f / C_DIM);
        float var = ss * (1.0f / C_DIM) - mean * mean;
        float rstd = rsqrtf(var + 1e-5f);
        bf16* dst = Bt + pl * 200 + seg * 48;
        for (int g = 0; g < 6; ++g) {
            bf16x8 w;
            for (int j = 0; j < 8; ++j) {
                int c = seg * 48 + g * 8 + j;
                w[j] = (bf16)((v[g * 8 + j] - mean) * rstd * gs[c] + bs[c]);
            }
            *(bf16x8*)(dst + g * 8) = w;
        }
    }
    __syncthreads();

    int l16 = lane & 15, quad = lane >> 4;
    int wm = (wave >> 1) * 32, wn = (wave & 1) * 32;
    f32x4 acc[2][2] = {};
    for (int kk = 0; kk < K; kk += 32) {
        const f32x4* ar0 = (const f32x4*)(wqkv + (m0 + wm + l16) * K + kk + quad * 8);
        const f32x4* ar1 = (const f32x4*)(wqkv + (m0 + wm + 16 + l16) * K + kk + quad * 8);
        f32x4 w0a = ar0[0], w0b = ar0[1];
        f32x4 w1a = ar1[0], w1b = ar1[1];
        bf16x8 a0, a1;
        for (int j = 0; j < 4; ++j) {
            a0[j] = (bf16)w0a[j]; a0[4 + j] = (bf16)w0b[j];
            a1[j] = (bf16)w1a[j]; a1[4 + j] = (bf16)w1b[j];
        }
        bf16x8 b0 = *(const bf16x8*)(Bt + (wn + l16) * 200 + kk + quad * 8);
        bf16x8 b1 = *(const bf16x8*)(Bt + (wn + 16 + l16) * 200 + kk + quad * 8);
        acc[0][0] = mfma16(a0, b0, acc[0][0]);
        acc[0][1] = mfma16(a0, b1, acc[0][1]);
        acc[1][0] = mfma16(a1, b0, acc[1][0]);
        acc[1][1] = mfma16(a1, b1, acc[1][1]);
    }
    for (int i = 0; i < 2; ++i)
        for (int j = 0; j < 2; ++j)
            for (int r = 0; r < 4; ++r) {
                int row = m0 + wm + i * 16 + quad * 4 + r;
                int col = n0 + wn + j * 16 + l16;
                qkvb[(size_t)row * N_PIX + col] = (bf16)acc[i][j][r];
            }
}

// ---------------- depthwise 3x3 + bias, vectorized; q/k stores via LDS transpose ----------------
__global__ __launch_bounds__(256) void dwconv(const bf16* __restrict__ qkv,
                                              const float* __restrict__ wdw,
                                              const float* __restrict__ bdw,
                                              bf16* __restrict__ qt,
                                              bf16* __restrict__ kt,
                                              bf16* __restrict__ vl,
                                              float* __restrict__ maxk2) {
    __shared__ float k2s[24][64];
    __shared__ bf16 stg[64 * DPAD];   // [px][ch], 4 KB
    int bx = blockIdx.x;
    int part = bx >> 9;            // 512 blocks per part
    int h = (bx >> 6) & 7;
    int y = bx & 63;
    int t = threadIdx.x;
    int ch_local = t >> 3;         // 0..31 (24 active)
    int seg = t & 7;
    int px0 = seg * 8;
    bool active = ch_local < 24;

    float acc[8];
    if (active) {
        int ch = part * C_DIM + h * DHEAD + ch_local;
        const bf16* in = qkv + (size_t)ch * N_PIX;
        float w[9];
        for (int i = 0; i < 9; ++i) w[i] = wdw[ch * 9 + i];
        float bias = bdw[ch];
        float rowv[3][10];
        for (int r = 0; r < 3; ++r) {
            int yy = y + r - 1;
            if (yy >= 0 && yy < 64) {
                bf16x8 v8 = *(const bf16x8*)(in + yy * 64 + px0);
                for (int j = 0; j < 8; ++j) rowv[r][j + 1] = (float)v8[j];
                rowv[r][0] = (seg > 0) ? (float)in[yy * 64 + px0 - 1] : 0.f;
                rowv[r][9] = (seg < 7) ? (float)in[yy * 64 + px0 + 8] : 0.f;
            } else {
                for (int j = 0; j < 10; ++j) rowv[r][j] = 0.f;
            }
        }
        for (int j = 0; j < 8; ++j) {
            float a = bias;
            for (int r = 0; r < 3; ++r)
                a += w[r * 3 + 0] * rowv[r][j] + w[r * 3 + 1] * rowv[r][j + 1]
                   + w[r * 3 + 2] * rowv[r][j + 2];
            acc[j] = a;
        }
    }

    if (part == 2) {
        if (active) {
            bf16x8 v8;
            for (int j = 0; j < 8; ++j) v8[j] = (bf16)acc[j];
            *(bf16x8*)(vl + ((size_t)(h * DPAD + ch_local)) * N_PIX + y * 64 + px0) = v8;
        } else {
            int i = t - 192;           // pad rows 24..31 x 8 segments
            int dd = 24 + (i >> 3);
            int s2 = i & 7;
            bf16 val = (bf16)((dd == 24) ? 1.0f : 0.0f);
            bf16x8 v8;
            for (int j = 0; j < 8; ++j) v8[j] = val;
            *(bf16x8*)(vl + ((size_t)(h * DPAD + dd)) * N_PIX + y * 64 + s2 * 8) = v8;
        }
    } else {
        if (active) {
            for (int j = 0; j < 8; ++j)
                stg[(px0 + j) * DPAD + ch_local] = (bf16)acc[j];
        } else {
            int i = t - 192;           // px = i: zero pad ch 24..31
            bf16x8 z;
            for (int j = 0; j < 8; ++j) z[j] = (bf16)0.0f;
            *(bf16x8*)(stg + i * DPAD + 24) = z;
        }
        if (part == 1 && active)
            for (int j = 0; j < 8; ++j) k2s[ch_local][px0 + j] = acc[j] * acc[j];
        __syncthreads();
        bf16* dst = (part == 0 ? qt : kt) + ((size_t)h * N_PIX + y * 64) * DPAD;
        *(bf16x8*)(dst + t * 8) = *(const bf16x8*)(stg + t * 8);
        if (part == 1 && t < 64) {
            float s = 0.f;
            for (int c = 0; c < 24; ++c) s += k2s[c][t];
            for (int off = 1; off < 64; off <<= 1)
                s = fmaxf(s, __shfl_xor(s, off, 64));
            if (t == 0) atomicMax((unsigned int*)(maxk2 + h), __float_as_uint(s));
        }
    }
}

// ---------------- flash attention: per-fragment LDS P buffers, K-prefetch pipeline, setprio core ----------------
__global__ __launch_bounds__(256, 4) void flash_attn(const bf16* __restrict__ qt,
                                                     const bf16* __restrict__ kt,
                                                     const bf16* __restrict__ vl,
                                                     const float* __restrict__ temp,
                                                     const float* __restrict__ maxk2,
                                                     bf16* __restrict__ opart,
                                                     bf16* __restrict__ lpart) {
    __shared__ __align__(16) bf16 Plds[16 * 1024];  // 8KB/wave: 4 fragments x 2KB each (no aliasing)

    int tid = threadIdx.x;
    int wave = tid >> 6, lane = tid & 63;
    int l16 = lane & 15, quad = lane >> 4;
    int head = blockIdx.x & 7;               // block -> XCD round-robin: head pinned per XCD
    int qb = (blockIdx.x >> 3) & 15;
    int split = blockIdx.x >> 7;             // 0..7
    int nbase = qb * 256 + wave * 64;
    float tl = temp[head] * 1.44269504f;

    const bf16* qrow = qt + ((size_t)head * N_PIX + nbase) * DPAD;
    bf16x8 aq[4];
    for (int f = 0; f < 4; ++f)
        aq[f] = *(const bf16x8*)(qrow + (size_t)(f * 16 + l16) * DPAD + quad * 8);

    float mk2 = maxk2[head];
    float Bb[4];
    for (int f = 0; f < 4; ++f) {
        float q2 = 0.f;
        for (int j = 0; j < 8; ++j) { float v = (float)aq[f][j]; q2 += v * v; }
        q2 += __shfl_xor(q2, 16, 64);
        q2 += __shfl_xor(q2, 32, 64);
        Bb[f] = fabsf(tl) * sqrtf(q2 * mk2) + 1.0f;
    }

    const bf16* kbase = kt + (size_t)head * N_PIX * DPAD;
    const bf16* vbase = vl + (size_t)head * DPAD * N_PIX;
    bf16* pw = Plds + wave * 4096;           // 4 x 1024 per wave

    f32x4 o0[4] = {}, o1[4] = {};

    const int NITER = 64 / NSPLIT;           // 8
    int mbase = split * NITER * 64;

    // prologue: K fragments for iter 0
    bf16x8 ak[4];
    for (int mt = 0; mt < 4; ++mt)
        ak[mt] = *(const bf16x8*)(kbase + (size_t)(mbase + mt * 16 + l16) * DPAD + quad * 8);

    #pragma unroll 2
    for (int it = 0; it < NITER; ++it) {
        int m0 = mbase + it * 64;
        // V fragments for this iter (consumed late -> latency self-hiding)
        bf16x8 av0 = *(const bf16x8*)(vbase + (size_t)l16 * N_PIX + m0 + quad * 8);
        bf16x8 av1 = *(const bf16x8*)(vbase + (size_t)(16 + l16) * N_PIX + m0 + quad * 8);
        bf16x8 av2 = *(const bf16x8*)(vbase + (size_t)l16 * N_PIX + m0 + 32 + quad * 8);
        bf16x8 av3 = *(const bf16x8*)(vbase + (size_t)(16 + l16) * N_PIX + m0 + 32 + quad * 8);
        // prefetch next iter's K fragments (the latency-exposed loads)
        bf16x8 akn[4];
        if (it + 1 < NITER) {
            int m1 = m0 + 64;
            for (int mt = 0; mt < 4; ++mt)
                akn[mt] = *(const bf16x8*)(kbase + (size_t)(m1 + mt * 16 + l16) * DPAD + quad * 8);
        }

        for (int f = 0; f < 4; ++f) {
            bf16* pwf = pw + f * 1024;       // private region per fragment -> no false DS deps
            __builtin_amdgcn_s_setprio(1);
            f32x4 z = {0.f, 0.f, 0.f, 0.f};
            f32x4 st[4];
            for (int mt = 0; mt < 4; ++mt) st[mt] = mfma16(ak[mt], aq[f], z);
            for (int mt = 0; mt < 4; ++mt) {
                bf16x4 pk;
                for (int r = 0; r < 4; ++r)
                    pk[r] = (bf16)fast_exp2(__builtin_fmaf(st[mt][r], tl, -Bb[f]));
                int chunk = mt * 2 + (quad >> 1);
                *(bf16x4*)(pwf + (chunk * 16 + l16) * 8 + (quad & 1) * 4) = pk;
            }
            bf16x8 ap0 = *(const bf16x8*)(pwf + (quad * 16 + l16) * 8);
            bf16x8 ap1 = *(const bf16x8*)(pwf + ((4 + quad) * 16 + l16) * 8);
            o0[f] = mfma16(av0, ap0, o0[f]);
            o1[f] = mfma16(av1, ap0, o1[f]);
            o0[f] = mfma16(av2, ap1, o0[f]);
            o1[f] = mfma16(av3, ap1, o1[f]);
            __builtin_amdgcn_s_setprio(0);
        }
        if (it + 1 < NITER)
            for (int mt = 0; mt < 4; ++mt) ak[mt] = akn[mt];
    }

    for (int f = 0; f < 4; ++f) {
        int n = nbase + f * 16 + l16;
        size_t rowo = ((size_t)(split * 8 + head) * N_PIX + n) * 24;
        bf16x4 w0;
        for (int r = 0; r < 4; ++r) w0[r] = (bf16)o0[f][r];
        *(bf16x4*)(opart + rowo + quad * 4) = w0;
        if (quad < 2) {
            bf16x4 w1;
            for (int r = 0; r < 4; ++r) w1[r] = (bf16)o1[f][r];
            *(bf16x4*)(opart + rowo + 16 + quad * 4) = w1;
        }
        if (quad == 2)
            lpart[(size_t)(split * 8 + head) * N_PIX + n] = (bf16)o1[f][0];
    }
}

// ---------------- proj GEMM with fused split-K combine; wproj converted inline ----------------
__global__ __launch_bounds__(256) void gemm_proj(const float* __restrict__ wproj,
                                                 const bf16* __restrict__ opart,
                                                 const bf16* __restrict__ lpart,
                                                 float* __restrict__ outf,
                                                 const float* __restrict__ resid) {
    __shared__ __align__(16) bf16 Bld[32 * 200];
    const int K = C_DIM;
    int n0 = blockIdx.x * 32;
    int m0 = blockIdx.y * 64;
    int t = threadIdx.x;
    {
        int h = t >> 5, nl = t & 31;
        int n = n0 + nl;
        float acc[24];
        for (int j = 0; j < 24; ++j) acc[j] = 0.f;
        float l = 0.f;
        for (int s = 0; s < NSPLIT; ++s) {
            const bf16* row = opart + ((size_t)(s * 8 + h) * N_PIX + n) * 24;
            bf16x8 a = *(const bf16x8*)(row);
            bf16x8 b = *(const bf16x8*)(row + 8);
            bf16x8 c = *(const bf16x8*)(row + 16);
            for (int j = 0; j < 8; ++j) {
                acc[j] += (float)a[j];
                acc[8 + j] += (float)b[j];
                acc[16 + j] += (float)c[j];
            }
            l += (float)lpart[(size_t)(s * 8 + h) * N_PIX + n];
        }
        float inv = 1.0f / l;
        bf16* dst = Bld + nl * 200 + h * 24;
        for (int g = 0; g < 3; ++g) {
            bf16x8 w;
            for (int j = 0; j < 8; ++j) w[j] = (bf16)(acc[g * 8 + j] * inv);
            *(bf16x8*)(dst + g * 8) = w;
        }
    }
    __syncthreads();
    int wave = t >> 6, lane = t & 63;
    int l16 = lane & 15, quad = lane >> 4;
    int mrow = m0 + wave * 16;
    float rv[8];
    for (int j = 0; j < 2; ++j)
        for (int r = 0; r < 4; ++r)
            rv[j * 4 + r] = resid[(size_t)(mrow + quad * 4 + r) * N_PIX + n0 + j * 16 + l16];
    f32x4 acc2[2] = {};
    for (int kk = 0; kk < K; kk += 32) {
        const f32x4* ar = (const f32x4*)(wproj + (mrow + l16) * K + kk + quad * 8);
        f32x4 wa = ar[0], wb = ar[1];
        bf16x8 a;
        for (int j = 0; j < 4; ++j) { a[j] = (bf16)wa[j]; a[4 + j] = (bf16)wb[j]; }
        bf16x8 b0 = *(const bf16x8*)(Bld + l16 * 200 + kk + quad * 8);
        bf16x8 b1 = *(const bf16x8*)(Bld + (16 + l16) * 200 + kk + quad * 8);
        acc2[0] = mfma16(a, b0, acc2[0]);
        acc2[1] = mfma16(a, b1, acc2[1]);
    }
    for (int j = 0; j < 2; ++j)
        for (int r = 0; r < 4; ++r) {
            int row = mrow + quad * 4 + r;
            int col = n0 + j * 16 + l16;
            outf[(size_t)row * N_PIX + col] = acc2[j][r] + rv[j * 4 + r];
        }
}

extern "C" void kernel_launch(void* const* d_in, const int* in_sizes, int n_in,
                              void* d_out, int out_size, void* d_ws, size_t ws_size,
                              hipStream_t stream) {
    const float* x     = (const float*)d_in[0];
    const float* gamma = (const float*)d_in[1];
    const float* beta  = (const float*)d_in[2];
    const float* wqkv  = (const float*)d_in[3];
    const float* wdw   = (const float*)d_in[4];
    const float* bdw   = (const float*)d_in[5];
    const float* wproj = (const float*)d_in[6];
    const float* temp  = (const float*)d_in[7];
    float* out = (float*)d_out;

    char* ws = (char*)d_ws;
    bf16* qkv     = (bf16*)(ws + 0);          // 576*4096*2 = 4718592
    bf16* qt      = (bf16*)(ws + 4718592);    // 2097152
    bf16* kt      = (bf16*)(ws + 6815744);    // 2097152
    bf16* vl      = (bf16*)(ws + 8912896);    // 2097152
    bf16* opart   = (bf16*)(ws + 11010048);   // 8*8*4096*24*2 = 12582912
    bf16* lpart   = (bf16*)(ws + 23592960);   // 8*8*4096*2 = 524288
    float* maxk2  = (float*)(ws + 24117248);  // 32

    ln_qkv<<<dim3(64, 9), 256, 0, stream>>>(x, gamma, beta, wqkv, qkv, maxk2);
    dwconv<<<1536, 256, 0, stream>>>(qkv, wdw, bdw, qt, kt, vl, maxk2);
    flash_attn<<<NSPLIT * 128, 256, 0, stream>>>(qt, kt, vl, temp, maxk2, opart, lpart);
    gemm_proj<<<dim3(128, 3), 256, 0, stream>>>(wproj, opart, lpart, out, x);
}